// Round 1
// baseline (213.934 us; speedup 1.0000x reference)
//
#include <hip/hip_runtime.h>
#include <hip/hip_bf16.h>
#include <float.h>
#include <limits.h>

#define NNODES 16384
#define KNB 8
#define HIDC 128

__device__ __forceinline__ bool keylt(float d1, int i1, float d2, int i2) {
  return (d1 < d2) || (d1 == d2 && i1 < i2);
}

// ---------------- KNN: one wave per node, segment scan + top-8 merge ----------------
__global__ __launch_bounds__(256) void knn_kernel(
    const float* __restrict__ coord, const int* __restrict__ batch,
    int* __restrict__ knn) {
  int n = (blockIdx.x * 256 + threadIdx.x) >> 6;  // wave id = node
  int lane = threadIdx.x & 63;
  if (n >= NNODES) return;
  int b = batch[n];
  // segment [s,e) of this node's graph (batch is sorted)
  int lo = 0, hi = NNODES;
  while (lo < hi) { int m = (lo + hi) >> 1; if (batch[m] < b) lo = m + 1; else hi = m; }
  int s = lo;
  lo = n; hi = NNODES;
  while (lo < hi) { int m = (lo + hi) >> 1; if (batch[m] <= b) lo = m + 1; else hi = m; }
  int e = lo;

  float cx = coord[n*3+0], cy = coord[n*3+1], cz = coord[n*3+2];
  float dist[KNB]; int ind[KNB];
  #pragma unroll
  for (int p = 0; p < KNB; ++p) { dist[p] = FLT_MAX; ind[p] = INT_MAX; }

  for (int j = s + lane; j < e; j += 64) {
    float dx = __fsub_rn(coord[j*3+0], cx);
    float dy = __fsub_rn(coord[j*3+1], cy);
    float dz = __fsub_rn(coord[j*3+2], cz);
    float d = __fadd_rn(__fadd_rn(__fmul_rn(dx,dx), __fmul_rn(dy,dy)), __fmul_rn(dz,dz));
    if (keylt(d, j, dist[KNB-1], ind[KNB-1])) {
      // unrolled sorted insert — all static indices (no scratch)
      #pragma unroll
      for (int p = KNB-1; p >= 0; --p) {
        bool shift = (p > 0) && keylt(d, j, dist[p-1], ind[p-1]);
        bool place = !shift && keylt(d, j, dist[p], ind[p]);
        float sd = (p > 0) ? dist[p-1] : 0.0f;
        int   si = (p > 0) ? ind[p-1] : 0;
        if (shift)      { dist[p] = sd; ind[p] = si; }
        else if (place) { dist[p] = d;  ind[p] = j;  }
      }
    }
  }
  // merge: 8 rounds of wave-wide butterfly min on key (d, id); winner pops its head
  int res = INT_MAX;
  #pragma unroll
  for (int t = 0; t < KNB; ++t) {
    float d = dist[0]; int id = ind[0];
    #pragma unroll
    for (int off = 32; off; off >>= 1) {
      float od = __shfl_xor(d, off);
      int  oid = __shfl_xor(id, off);
      if (keylt(od, oid, d, id)) { d = od; id = oid; }
    }
    if (ind[0] == id && dist[0] == d) {  // unique winner (ids unique) pops
      #pragma unroll
      for (int p = 0; p < KNB-1; ++p) { dist[p] = dist[p+1]; ind[p] = ind[p+1]; }
      dist[KNB-1] = FLT_MAX; ind[KNB-1] = INT_MAX;
    }
    if (lane == t) res = id;
  }
  if (lane < KNB) knn[n*KNB + lane] = res;
}

// ---------------- xl = x@Wl + bl ; xr = x@Wr + br  (fused, reg-tiled) ----------------
template<int K>
__global__ __launch_bounds__(256) void lin2_kernel(
    const float* __restrict__ x,
    const float* __restrict__ Wl, const float* __restrict__ bl,
    const float* __restrict__ Wr, const float* __restrict__ br,
    float* __restrict__ xl, float* __restrict__ xr) {
  __shared__ float xs[64 * K];
  int t = threadIdx.x;
  int node0 = blockIdx.x * 64;
  for (int i = t; i < 64 * K; i += 256) xs[i] = x[node0 * K + i];
  __syncthreads();
  int cg = t & 63;        // 64 col-groups of 4 cols each (256 combined cols)
  int ng = t >> 6;        // 4 node-groups of 16 nodes
  int c0 = cg * 4;
  bool isR = (c0 >= HIDC);
  const float* W    = isR ? Wr : Wl;
  const float* bias = isR ? br : bl;
  float* dst        = isR ? xr : xl;
  int wc = isR ? (c0 - HIDC) : c0;

  float acc[16][4];
  #pragma unroll
  for (int nn = 0; nn < 16; ++nn) { acc[nn][0]=0.f; acc[nn][1]=0.f; acc[nn][2]=0.f; acc[nn][3]=0.f; }

  for (int k = 0; k < K; ++k) {
    float4 w = *(const float4*)(W + k * HIDC + wc);
    #pragma unroll
    for (int nn = 0; nn < 16; ++nn) {
      float xv = xs[(ng * 16 + nn) * K + k];  // wave-uniform LDS broadcast
      acc[nn][0] = fmaf(xv, w.x, acc[nn][0]);
      acc[nn][1] = fmaf(xv, w.y, acc[nn][1]);
      acc[nn][2] = fmaf(xv, w.z, acc[nn][2]);
      acc[nn][3] = fmaf(xv, w.w, acc[nn][3]);
    }
  }
  float4 b4 = *(const float4*)(bias + wc);
  #pragma unroll
  for (int nn = 0; nn < 16; ++nn) {
    int node = node0 + ng * 16 + nn;
    float4 o;
    o.x = acc[nn][0] + b4.x; o.y = acc[nn][1] + b4.y;
    o.z = acc[nn][2] + b4.z; o.w = acc[nn][3] + b4.w;
    *(float4*)(dst + node * HIDC + wc) = o;
  }
}

// ---------------- GATv2 attention + aggregate + bias + relu (wave per node) ----------------
__global__ __launch_bounds__(256) void gat_attn_kernel(
    const float* __restrict__ xl, const float* __restrict__ xr,
    const int* __restrict__ knn, const float* __restrict__ att,
    const float* __restrict__ bias, float* __restrict__ xout) {
  int wid = threadIdx.x >> 6;
  int lane = threadIdx.x & 63;
  int n = blockIdx.x * 4 + wid;
  int c0 = lane, c1 = lane + 64;
  float xr0 = xr[n * HIDC + c0], xr1 = xr[n * HIDC + c1];
  float a0 = att[c0], a1 = att[c1];
  float g0[8], g1[8], lg[8];
  #pragma unroll
  for (int k = 0; k < 8; ++k) {
    int j = knn[n * 8 + k];
    g0[k] = xl[j * HIDC + c0];
    g1[k] = xl[j * HIDC + c1];
    float e0 = g0[k] + xr0; e0 = (e0 > 0.f) ? e0 : 0.2f * e0;
    float e1 = g1[k] + xr1; e1 = (e1 > 0.f) ? e1 : 0.2f * e1;
    float p = e0 * a0 + e1 * a1;
    #pragma unroll
    for (int off = 32; off; off >>= 1) p += __shfl_xor(p, off);
    lg[k] = p;
  }
  float m = lg[0];
  #pragma unroll
  for (int k = 1; k < 8; ++k) m = fmaxf(m, lg[k]);
  float s = 0.f, w[8];
  #pragma unroll
  for (int k = 0; k < 8; ++k) { w[k] = __expf(lg[k] - m); s += w[k]; }
  float inv = 1.f / s;
  float o0 = 0.f, o1 = 0.f;
  #pragma unroll
  for (int k = 0; k < 8; ++k) { o0 += w[k] * g0[k]; o1 += w[k] * g1[k]; }
  o0 = fmaxf(fmaf(o0, inv, bias[c0]), 0.f);
  o1 = fmaxf(fmaf(o1, inv, bias[c1]), 0.f);
  xout[n * HIDC + c0] = o0;
  xout[n * HIDC + c1] = o1;
}

// ---------------- final linear: out = x @ Wf + bf  ([N,128]x[128,3]) ----------------
__global__ __launch_bounds__(256) void final_kernel(
    const float* __restrict__ x, const float* __restrict__ Wf,
    const float* __restrict__ bf, float* __restrict__ out) {
  __shared__ float w[384];
  __shared__ float b[3];
  int t = threadIdx.x;
  for (int i = t; i < 384; i += 256) w[i] = Wf[i];
  if (t < 3) b[t] = bf[t];
  __syncthreads();
  int n = blockIdx.x * 256 + t;
  float a0 = b[0], a1 = b[1], a2 = b[2];
  const float4* xp = (const float4*)(x + n * HIDC);
  #pragma unroll 8
  for (int k4 = 0; k4 < 32; ++k4) {
    float4 xv = xp[k4];
    const float* wk = &w[k4 * 12];
    a0 += xv.x * wk[0] + xv.y * wk[3] + xv.z * wk[6] + xv.w * wk[9];
    a1 += xv.x * wk[1] + xv.y * wk[4] + xv.z * wk[7] + xv.w * wk[10];
    a2 += xv.x * wk[2] + xv.y * wk[5] + xv.z * wk[8] + xv.w * wk[11];
  }
  out[n * 3 + 0] = a0;
  out[n * 3 + 1] = a1;
  out[n * 3 + 2] = a2;
}

extern "C" void kernel_launch(void* const* d_in, const int* in_sizes, int n_in,
                              void* d_out, int out_size, void* d_ws, size_t ws_size,
                              hipStream_t stream) {
  const float* coord = (const float*)d_in[0];
  const float* feat  = (const float*)d_in[1];
  const int*   batch = (const int*)d_in[2];
  const float* Wl0 = (const float*)d_in[3];
  const float* bl0 = (const float*)d_in[4];
  const float* Wr0 = (const float*)d_in[5];
  const float* br0 = (const float*)d_in[6];
  const float* att0  = (const float*)d_in[7];
  const float* bias0 = (const float*)d_in[8];
  const float* Wl1 = (const float*)d_in[9];
  const float* bl1 = (const float*)d_in[10];
  const float* Wr1 = (const float*)d_in[11];
  const float* br1 = (const float*)d_in[12];
  const float* att1  = (const float*)d_in[13];
  const float* bias1 = (const float*)d_in[14];
  const float* Wl2 = (const float*)d_in[15];
  const float* bl2 = (const float*)d_in[16];
  const float* Wr2 = (const float*)d_in[17];
  const float* br2 = (const float*)d_in[18];
  const float* att2  = (const float*)d_in[19];
  const float* bias2 = (const float*)d_in[20];
  const float* Wf = (const float*)d_in[21];
  const float* bf = (const float*)d_in[22];
  float* out = (float*)d_out;

  char* ws = (char*)d_ws;
  int*   knn = (int*)ws;                                   // 512 KB
  float* xl  = (float*)(ws + (512 << 10));                 // 8 MB
  float* xr  = xl + (size_t)NNODES * HIDC;                 // 8 MB
  float* xb0 = xr + (size_t)NNODES * HIDC;                 // 8 MB
  float* xb1 = xb0 + (size_t)NNODES * HIDC;                // 8 MB

  knn_kernel<<<NNODES * 64 / 256, 256, 0, stream>>>(coord, batch, knn);

  lin2_kernel<6><<<NNODES / 64, 256, 0, stream>>>(feat, Wl0, bl0, Wr0, br0, xl, xr);
  gat_attn_kernel<<<NNODES / 4, 256, 0, stream>>>(xl, xr, knn, att0, bias0, xb0);

  lin2_kernel<128><<<NNODES / 64, 256, 0, stream>>>(xb0, Wl1, bl1, Wr1, br1, xl, xr);
  gat_attn_kernel<<<NNODES / 4, 256, 0, stream>>>(xl, xr, knn, att1, bias1, xb1);

  lin2_kernel<128><<<NNODES / 64, 256, 0, stream>>>(xb1, Wl2, bl2, Wr2, br2, xl, xr);
  gat_attn_kernel<<<NNODES / 4, 256, 0, stream>>>(xl, xr, knn, att2, bias2, xb0);

  final_kernel<<<NNODES / 256, 256, 0, stream>>>(xb0, Wf, bf, out);
}

// Round 2
// 185.262 us; speedup vs baseline: 1.1548x; 1.1548x over previous
//
#include <hip/hip_runtime.h>
#include <hip/hip_bf16.h>
#include <float.h>
#include <limits.h>

#define NNODES 16384
#define KNB 8
#define HIDC 128

__device__ __forceinline__ bool keylt(float d1, int i1, float d2, int i2) {
  return (d1 < d2) || (d1 == d2 && i1 < i2);
}

// ---------------- KNN: one wave per node, distributed top-8 + ballot survivor loop --------
// Lane l (l<8) holds the (l+1)-th smallest (d, idx) seen so far, sorted ascending.
__global__ __launch_bounds__(256) void knn_kernel(
    const float* __restrict__ coord, const int* __restrict__ batch,
    int* __restrict__ knn) {
  int n = (blockIdx.x * 256 + threadIdx.x) >> 6;  // wave id = node
  int lane = threadIdx.x & 63;
  int b = batch[n];
  // segment [s,e) of this node's graph (batch is sorted)
  int lo = 0, hi = NNODES;
  while (lo < hi) { int m = (lo + hi) >> 1; if (batch[m] < b) lo = m + 1; else hi = m; }
  int s = lo;
  lo = n; hi = NNODES;
  while (lo < hi) { int m = (lo + hi) >> 1; if (batch[m] <= b) lo = m + 1; else hi = m; }
  int e = lo;

  float cx = coord[n*3+0], cy = coord[n*3+1], cz = coord[n*3+2];

  // --- cold start: exact top-8 of batch 0 via 8 butterfly-argmin rounds ---
  float val = FLT_MAX; int vidx = INT_MAX;     // distributed sorted list (lanes 0..7)
  int j0 = s + lane;
  float d0 = FLT_MAX;
  if (j0 < e) {
    float dx = __fsub_rn(coord[j0*3+0], cx);
    float dy = __fsub_rn(coord[j0*3+1], cy);
    float dz = __fsub_rn(coord[j0*3+2], cz);
    d0 = __fadd_rn(__fadd_rn(__fmul_rn(dx,dx), __fmul_rn(dy,dy)), __fmul_rn(dz,dz));
  } else {
    j0 = INT_MAX;
  }
  #pragma unroll
  for (int r = 0; r < KNB; ++r) {
    float dd = d0; int ii = j0;
    #pragma unroll
    for (int off = 32; off; off >>= 1) {
      float od = __shfl_xor(dd, off);
      int  oi = __shfl_xor(ii, off);
      if (keylt(od, oi, dd, ii)) { dd = od; ii = oi; }
    }
    if (lane == r) { val = dd; vidx = ii; }
    if (j0 == ii) { d0 = FLT_MAX; j0 = INT_MAX; }
  }
  float taud = __shfl(val, 7); int taui = __shfl(vidx, 7);

  // --- main scan: filter vs tau, insert rare survivors ---
  for (int base = s + 64; base < e; base += 64) {
    int j = base + lane;
    bool ok = j < e;
    int jc = ok ? j : s;
    float dx = __fsub_rn(coord[jc*3+0], cx);
    float dy = __fsub_rn(coord[jc*3+1], cy);
    float dz = __fsub_rn(coord[jc*3+2], cz);
    float d = __fadd_rn(__fadd_rn(__fmul_rn(dx,dx), __fmul_rn(dy,dy)), __fmul_rn(dz,dz));
    bool survive = ok && keylt(d, j, taud, taui);
    unsigned long long m = __ballot(survive);
    while (m) {
      int src = __ffsll((long long)m) - 1;
      m &= m - 1;
      float dn = __shfl(d, src);
      int   jn = __shfl(j, src);
      float prevv = __shfl_up(val, 1);
      int   previ = __shfl_up(vidx, 1);
      if (lane == 0) { prevv = -FLT_MAX; previ = INT_MIN; }
      bool ins = keylt(dn, jn, val, vidx);
      bool fromprev = keylt(dn, jn, prevv, previ);
      float nv = fromprev ? prevv : dn;
      int   ni = fromprev ? previ : jn;
      if (ins) { val = nv; vidx = ni; }
    }
    if (m != 0ull || true) { taud = __shfl(val, 7); taui = __shfl(vidx, 7); }
  }
  if (lane < KNB) knn[n*KNB + lane] = vidx;
}

// ---------------- xl = x@Wl + bl ; xr = x@Wr + br  (fused, reg-tiled, 32-node tiles) ------
template<int K>
__global__ __launch_bounds__(256) void lin2_kernel(
    const float* __restrict__ x,
    const float* __restrict__ Wl, const float* __restrict__ bl,
    const float* __restrict__ Wr, const float* __restrict__ br,
    float* __restrict__ xl, float* __restrict__ xr) {
  __shared__ float xs[32 * K];
  int t = threadIdx.x;
  int node0 = blockIdx.x * 32;
  for (int i = t; i < 32 * K; i += 256) xs[i] = x[node0 * K + i];
  __syncthreads();
  int cg = t & 63;        // 64 col-groups of 4 cols each (256 combined cols)
  int ng = t >> 6;        // 4 node-groups of 8 nodes
  int c0 = cg * 4;
  bool isR = (c0 >= HIDC);
  const float* W    = isR ? Wr : Wl;
  const float* bias = isR ? br : bl;
  float* dst        = isR ? xr : xl;
  int wc = isR ? (c0 - HIDC) : c0;

  float acc[8][4];
  #pragma unroll
  for (int nn = 0; nn < 8; ++nn) { acc[nn][0]=0.f; acc[nn][1]=0.f; acc[nn][2]=0.f; acc[nn][3]=0.f; }

  #pragma unroll 2
  for (int k = 0; k < K; ++k) {
    float4 w = *(const float4*)(W + k * HIDC + wc);
    #pragma unroll
    for (int nn = 0; nn < 8; ++nn) {
      float xv = xs[(ng * 8 + nn) * K + k];  // wave-uniform LDS broadcast
      acc[nn][0] = fmaf(xv, w.x, acc[nn][0]);
      acc[nn][1] = fmaf(xv, w.y, acc[nn][1]);
      acc[nn][2] = fmaf(xv, w.z, acc[nn][2]);
      acc[nn][3] = fmaf(xv, w.w, acc[nn][3]);
    }
  }
  float4 b4 = *(const float4*)(bias + wc);
  #pragma unroll
  for (int nn = 0; nn < 8; ++nn) {
    int node = node0 + ng * 8 + nn;
    float4 o;
    o.x = acc[nn][0] + b4.x; o.y = acc[nn][1] + b4.y;
    o.z = acc[nn][2] + b4.z; o.w = acc[nn][3] + b4.w;
    *(float4*)(dst + node * HIDC + wc) = o;
  }
}

// -------- GATv2 attention + aggregate + bias + relu (wave per node), optional fused final --
template<bool FINAL>
__global__ __launch_bounds__(256) void gat_attn_kernel(
    const float* __restrict__ xl, const float* __restrict__ xr,
    const int* __restrict__ knn, const float* __restrict__ att,
    const float* __restrict__ bias, float* __restrict__ xout,
    const float* __restrict__ Wf, const float* __restrict__ bf,
    float* __restrict__ out) {
  int wid = threadIdx.x >> 6;
  int lane = threadIdx.x & 63;
  int n = blockIdx.x * 4 + wid;
  int c0 = lane, c1 = lane + 64;
  float xr0 = xr[n * HIDC + c0], xr1 = xr[n * HIDC + c1];
  float a0 = att[c0], a1 = att[c1];
  float g0[8], g1[8], lg[8];
  #pragma unroll
  for (int k = 0; k < 8; ++k) {
    int j = knn[n * 8 + k];
    g0[k] = xl[j * HIDC + c0];
    g1[k] = xl[j * HIDC + c1];
    float e0 = g0[k] + xr0; e0 = (e0 > 0.f) ? e0 : 0.2f * e0;
    float e1 = g1[k] + xr1; e1 = (e1 > 0.f) ? e1 : 0.2f * e1;
    float p = e0 * a0 + e1 * a1;
    #pragma unroll
    for (int off = 32; off; off >>= 1) p += __shfl_xor(p, off);
    lg[k] = p;
  }
  float mx = lg[0];
  #pragma unroll
  for (int k = 1; k < 8; ++k) mx = fmaxf(mx, lg[k]);
  float ssum = 0.f, w[8];
  #pragma unroll
  for (int k = 0; k < 8; ++k) { w[k] = __expf(lg[k] - mx); ssum += w[k]; }
  float inv = 1.f / ssum;
  float o0 = 0.f, o1 = 0.f;
  #pragma unroll
  for (int k = 0; k < 8; ++k) { o0 += w[k] * g0[k]; o1 += w[k] * g1[k]; }
  o0 = fmaxf(fmaf(o0, inv, bias[c0]), 0.f);
  o1 = fmaxf(fmaf(o1, inv, bias[c1]), 0.f);
  if (!FINAL) {
    xout[n * HIDC + c0] = o0;
    xout[n * HIDC + c1] = o1;
  } else {
    #pragma unroll
    for (int cls = 0; cls < 3; ++cls) {
      float p = o0 * Wf[c0 * 3 + cls] + o1 * Wf[c1 * 3 + cls];
      #pragma unroll
      for (int off = 32; off; off >>= 1) p += __shfl_xor(p, off);
      if (lane == 0) out[n * 3 + cls] = p + bf[cls];
    }
  }
}

extern "C" void kernel_launch(void* const* d_in, const int* in_sizes, int n_in,
                              void* d_out, int out_size, void* d_ws, size_t ws_size,
                              hipStream_t stream) {
  const float* coord = (const float*)d_in[0];
  const float* feat  = (const float*)d_in[1];
  const int*   batch = (const int*)d_in[2];
  const float* Wl0 = (const float*)d_in[3];
  const float* bl0 = (const float*)d_in[4];
  const float* Wr0 = (const float*)d_in[5];
  const float* br0 = (const float*)d_in[6];
  const float* att0  = (const float*)d_in[7];
  const float* bias0 = (const float*)d_in[8];
  const float* Wl1 = (const float*)d_in[9];
  const float* bl1 = (const float*)d_in[10];
  const float* Wr1 = (const float*)d_in[11];
  const float* br1 = (const float*)d_in[12];
  const float* att1  = (const float*)d_in[13];
  const float* bias1 = (const float*)d_in[14];
  const float* Wl2 = (const float*)d_in[15];
  const float* bl2 = (const float*)d_in[16];
  const float* Wr2 = (const float*)d_in[17];
  const float* br2 = (const float*)d_in[18];
  const float* att2  = (const float*)d_in[19];
  const float* bias2 = (const float*)d_in[20];
  const float* Wf = (const float*)d_in[21];
  const float* bf = (const float*)d_in[22];
  float* out = (float*)d_out;

  char* ws = (char*)d_ws;
  int*   knn = (int*)ws;                                   // 512 KB
  float* xl  = (float*)(ws + (512 << 10));                 // 8 MB
  float* xr  = xl + (size_t)NNODES * HIDC;                 // 8 MB
  float* xb0 = xr + (size_t)NNODES * HIDC;                 // 8 MB
  float* xb1 = xb0 + (size_t)NNODES * HIDC;                // 8 MB

  knn_kernel<<<NNODES * 64 / 256, 256, 0, stream>>>(coord, batch, knn);

  lin2_kernel<6><<<NNODES / 32, 256, 0, stream>>>(feat, Wl0, bl0, Wr0, br0, xl, xr);
  gat_attn_kernel<false><<<NNODES / 4, 256, 0, stream>>>(xl, xr, knn, att0, bias0, xb0,
                                                         nullptr, nullptr, nullptr);

  lin2_kernel<128><<<NNODES / 32, 256, 0, stream>>>(xb0, Wl1, bl1, Wr1, br1, xl, xr);
  gat_attn_kernel<false><<<NNODES / 4, 256, 0, stream>>>(xl, xr, knn, att1, bias1, xb1,
                                                         nullptr, nullptr, nullptr);

  lin2_kernel<128><<<NNODES / 32, 256, 0, stream>>>(xb1, Wl2, bl2, Wr2, br2, xl, xr);
  gat_attn_kernel<true><<<NNODES / 4, 256, 0, stream>>>(xl, xr, knn, att2, bias2, nullptr,
                                                        Wf, bf, out);
}

// Round 3
// 166.668 us; speedup vs baseline: 1.2836x; 1.1116x over previous
//
#include <hip/hip_runtime.h>
#include <hip/hip_bf16.h>
#include <float.h>
#include <limits.h>

#define NNODES 16384
#define KNB 8
#define HIDC 128
#define KNN_CAP 2560   // LDS candidate window (float4 each = 40KB)

// -------- DPP helpers (pure-VALU cross-lane) --------
__device__ __forceinline__ unsigned int dpp_shr1_u32(unsigned int v) {
  // row_shr:1 (0x111); bound_ctrl=1 -> invalid lanes (lane 0 of each row) read 0
  return (unsigned int)__builtin_amdgcn_update_dpp(0, (int)v, 0x111, 0xF, 0xF, true);
}
__device__ __forceinline__ float wave_sum(float x) {
  x += __int_as_float(__builtin_amdgcn_update_dpp(0, __float_as_int(x), 0xB1, 0xF, 0xF, true));  // quad xor1
  x += __int_as_float(__builtin_amdgcn_update_dpp(0, __float_as_int(x), 0x4E, 0xF, 0xF, true));  // quad xor2
  x += __int_as_float(__builtin_amdgcn_update_dpp(0, __float_as_int(x), 0x124, 0xF, 0xF, true)); // row_ror:4
  x += __int_as_float(__builtin_amdgcn_update_dpp(0, __float_as_int(x), 0x128, 0xF, 0xF, true)); // row_ror:8
  float r0 = __int_as_float(__builtin_amdgcn_readlane(__float_as_int(x), 0));
  float r1 = __int_as_float(__builtin_amdgcn_readlane(__float_as_int(x), 16));
  float r2 = __int_as_float(__builtin_amdgcn_readlane(__float_as_int(x), 32));
  float r3 = __int_as_float(__builtin_amdgcn_readlane(__float_as_int(x), 48));
  return (r0 + r1) + (r2 + r3);
}

// ---------------- KNN ----------------
// Block = 512 threads (8 waves) = 8 consecutive query nodes sharing one LDS
// candidate window. Per wave: distributed sorted top-8 as u64 keys in lanes
// 0..7; ballot filter vs tau; insertion = readlane broadcast + DPP shift
// (no ds_bpermute anywhere in the hot path).
__global__ __launch_bounds__(512) void knn_kernel(
    const float* __restrict__ coord, const int* __restrict__ batch,
    int* __restrict__ knn) {
  __shared__ float4 tile[KNN_CAP];
  int t = threadIdx.x;
  int lane = t & 63;
  int n0 = blockIdx.x * 8;
  int n = n0 + (t >> 6);

  int b0 = batch[n0], b7 = batch[n0 + 7], bw = batch[n];
  // lower_bound(b0)
  int lo = 0, hi = NNODES;
  while (lo < hi) { int m = (lo + hi) >> 1; if (batch[m] < b0) lo = m + 1; else hi = m; }
  int smin = lo;
  // upper_bound(b7)
  lo = n0 + 7; hi = NNODES;
  while (lo < hi) { int m = (lo + hi) >> 1; if (batch[m] <= b7) lo = m + 1; else hi = m; }
  int emax = lo;
  int s_w = smin, e_w = emax;
  if (bw != b0) {   // rare straddle
    lo = n0; hi = NNODES;
    while (lo < hi) { int m = (lo + hi) >> 1; if (batch[m] < bw) lo = m + 1; else hi = m; }
    s_w = lo;
  }
  if (bw != b7) {
    lo = n; hi = NNODES;
    while (lo < hi) { int m = (lo + hi) >> 1; if (batch[m] <= bw) lo = m + 1; else hi = m; }
    e_w = lo;
  }
  int win_end = min(emax, smin + KNN_CAP);
  int cnt = win_end - smin;

  // cooperative fill of candidate window
  for (int i = t; i < cnt; i += 512) {
    const float* cp = coord + (size_t)(smin + i) * 3;
    tile[i] = make_float4(cp[0], cp[1], cp[2], 0.f);
  }
  __syncthreads();

  float cx = coord[n*3+0], cy = coord[n*3+1], cz = coord[n*3+2];

  unsigned long long tau = ~0ull;
  unsigned int llo = 0xFFFFFFFFu, lhi = 0xFFFFFFFFu;  // lanes 0..7: sorted keys

  int lo_i = s_w - smin;
  int hi_i = min(e_w, win_end) - smin;
  for (int base = lo_i; base < hi_i; base += 64) {
    int i = base + lane;
    bool ok = i < hi_i;
    int ic = ok ? i : lo_i;
    float4 c = tile[ic];
    float dx = __fsub_rn(c.x, cx);
    float dy = __fsub_rn(c.y, cy);
    float dz = __fsub_rn(c.z, cz);
    float d = __fadd_rn(__fadd_rn(__fmul_rn(dx,dx), __fmul_rn(dy,dy)), __fmul_rn(dz,dz));
    unsigned long long ckey = ok
        ? (((unsigned long long)__float_as_uint(d) << 32) | (unsigned int)(smin + i))
        : ~0ull;
    unsigned long long m = __ballot(ckey < tau);
    if (m) {
      unsigned int c_lo = (unsigned int)ckey;
      unsigned int c_hi = (unsigned int)(ckey >> 32);
      do {
        int src = __builtin_ctzll(m);
        m &= m - 1;
        unsigned int nlo = (unsigned int)__builtin_amdgcn_readlane((int)c_lo, src);
        unsigned int nhi = (unsigned int)__builtin_amdgcn_readlane((int)c_hi, src);
        unsigned long long nk = ((unsigned long long)nhi << 32) | nlo;
        unsigned int plo = dpp_shr1_u32(llo);
        unsigned int phi = dpp_shr1_u32(lhi);
        unsigned long long pk = ((unsigned long long)phi << 32) | plo;
        unsigned long long ck = ((unsigned long long)lhi << 32) | llo;
        if (nk < ck) {
          unsigned long long r = (pk > nk) ? pk : nk;
          llo = (unsigned int)r; lhi = (unsigned int)(r >> 32);
        }
      } while (m);
      tau = (((unsigned long long)(unsigned int)__builtin_amdgcn_readlane((int)lhi, 7)) << 32)
            | (unsigned int)__builtin_amdgcn_readlane((int)llo, 7);
    }
  }
  // global-read tail for window overflow (rare; correctness only)
  for (int base = max(s_w, win_end); base < e_w; base += 64) {
    int j = base + lane;
    bool ok = j < e_w;
    int jc = ok ? j : s_w;
    float dx = __fsub_rn(coord[jc*3+0], cx);
    float dy = __fsub_rn(coord[jc*3+1], cy);
    float dz = __fsub_rn(coord[jc*3+2], cz);
    float d = __fadd_rn(__fadd_rn(__fmul_rn(dx,dx), __fmul_rn(dy,dy)), __fmul_rn(dz,dz));
    unsigned long long ckey = ok
        ? (((unsigned long long)__float_as_uint(d) << 32) | (unsigned int)j)
        : ~0ull;
    unsigned long long m = __ballot(ckey < tau);
    if (m) {
      unsigned int c_lo = (unsigned int)ckey;
      unsigned int c_hi = (unsigned int)(ckey >> 32);
      do {
        int src = __builtin_ctzll(m);
        m &= m - 1;
        unsigned int nlo = (unsigned int)__builtin_amdgcn_readlane((int)c_lo, src);
        unsigned int nhi = (unsigned int)__builtin_amdgcn_readlane((int)c_hi, src);
        unsigned long long nk = ((unsigned long long)nhi << 32) | nlo;
        unsigned int plo = dpp_shr1_u32(llo);
        unsigned int phi = dpp_shr1_u32(lhi);
        unsigned long long pk = ((unsigned long long)phi << 32) | plo;
        unsigned long long ck = ((unsigned long long)lhi << 32) | llo;
        if (nk < ck) {
          unsigned long long r = (pk > nk) ? pk : nk;
          llo = (unsigned int)r; lhi = (unsigned int)(r >> 32);
        }
      } while (m);
      tau = (((unsigned long long)(unsigned int)__builtin_amdgcn_readlane((int)lhi, 7)) << 32)
            | (unsigned int)__builtin_amdgcn_readlane((int)llo, 7);
    }
  }
  if (lane < KNB) knn[n*KNB + lane] = (int)llo;
}

// ---------------- xl = x@Wl + bl ; xr = x@Wr + br  (fused, 32-node tiles) ----------------
template<int K>
__global__ __launch_bounds__(256) void lin2_kernel(
    const float* __restrict__ x,
    const float* __restrict__ Wl, const float* __restrict__ bl,
    const float* __restrict__ Wr, const float* __restrict__ br,
    float* __restrict__ xl, float* __restrict__ xr) {
  __shared__ float xs[32 * K];
  int t = threadIdx.x;
  int node0 = blockIdx.x * 32;
  for (int i = t; i < 32 * K; i += 256) xs[i] = x[node0 * K + i];
  __syncthreads();
  int cg = t & 63;        // 64 col-groups x 4 cols = 256 combined cols
  int ng = t >> 6;        // 4 node-groups x 8 nodes
  int c0 = cg * 4;
  bool isR = (c0 >= HIDC);
  const float* W    = isR ? Wr : Wl;
  const float* bias = isR ? br : bl;
  float* dst        = isR ? xr : xl;
  int wc = isR ? (c0 - HIDC) : c0;

  float4 acc[8];
  #pragma unroll
  for (int nn = 0; nn < 8; ++nn) acc[nn] = make_float4(0.f, 0.f, 0.f, 0.f);

  if constexpr (K % 4 == 0) {
    for (int k0 = 0; k0 < K; k0 += 4) {
      float4 xv[8];
      #pragma unroll
      for (int nn = 0; nn < 8; ++nn)
        xv[nn] = *(const float4*)&xs[(ng * 8 + nn) * K + k0];  // uniform-addr broadcast
      #pragma unroll
      for (int q = 0; q < 4; ++q) {
        float4 w = *(const float4*)(W + (size_t)(k0 + q) * HIDC + wc);
        #pragma unroll
        for (int nn = 0; nn < 8; ++nn) {
          float xq = (q == 0) ? xv[nn].x : (q == 1) ? xv[nn].y : (q == 2) ? xv[nn].z : xv[nn].w;
          acc[nn].x = fmaf(xq, w.x, acc[nn].x);
          acc[nn].y = fmaf(xq, w.y, acc[nn].y);
          acc[nn].z = fmaf(xq, w.z, acc[nn].z);
          acc[nn].w = fmaf(xq, w.w, acc[nn].w);
        }
      }
    }
  } else {
    for (int k = 0; k < K; ++k) {
      float4 w = *(const float4*)(W + (size_t)k * HIDC + wc);
      #pragma unroll
      for (int nn = 0; nn < 8; ++nn) {
        float xq = xs[(ng * 8 + nn) * K + k];
        acc[nn].x = fmaf(xq, w.x, acc[nn].x);
        acc[nn].y = fmaf(xq, w.y, acc[nn].y);
        acc[nn].z = fmaf(xq, w.z, acc[nn].z);
        acc[nn].w = fmaf(xq, w.w, acc[nn].w);
      }
    }
  }
  float4 b4 = *(const float4*)(bias + wc);
  #pragma unroll
  for (int nn = 0; nn < 8; ++nn) {
    int node = node0 + ng * 8 + nn;
    float4 o;
    o.x = acc[nn].x + b4.x; o.y = acc[nn].y + b4.y;
    o.z = acc[nn].z + b4.z; o.w = acc[nn].w + b4.w;
    *(float4*)(dst + (size_t)node * HIDC + wc) = o;
  }
}

// -------- GATv2 attention + aggregate + bias + relu (wave per node), optional fused final --
template<bool FINAL>
__global__ __launch_bounds__(256) void gat_attn_kernel(
    const float* __restrict__ xl, const float* __restrict__ xr,
    const int* __restrict__ knn, const float* __restrict__ att,
    const float* __restrict__ bias, float* __restrict__ xout,
    const float* __restrict__ Wf, const float* __restrict__ bf,
    float* __restrict__ out) {
  int wid = threadIdx.x >> 6;
  int lane = threadIdx.x & 63;
  int n = blockIdx.x * 4 + wid;
  int c0 = 2 * lane, c1 = 2 * lane + 1;
  float2 xr2 = *(const float2*)(xr + (size_t)n * HIDC + c0);
  float2 a2  = *(const float2*)(att + c0);
  int myj = (lane < KNB) ? knn[n * KNB + lane] : 0;
  float g0[8], g1[8], lg[8];
  #pragma unroll
  for (int k = 0; k < 8; ++k) {
    int j = __builtin_amdgcn_readlane(myj, k);
    float2 g = *(const float2*)(xl + (size_t)j * HIDC + c0);
    g0[k] = g.x; g1[k] = g.y;
    float e0 = g.x + xr2.x; e0 = (e0 > 0.f) ? e0 : 0.2f * e0;
    float e1 = g.y + xr2.y; e1 = (e1 > 0.f) ? e1 : 0.2f * e1;
    lg[k] = wave_sum(e0 * a2.x + e1 * a2.y);
  }
  float mx = lg[0];
  #pragma unroll
  for (int k = 1; k < 8; ++k) mx = fmaxf(mx, lg[k]);
  float ssum = 0.f, w[8];
  #pragma unroll
  for (int k = 0; k < 8; ++k) { w[k] = __expf(lg[k] - mx); ssum += w[k]; }
  float inv = 1.f / ssum;
  float o0 = 0.f, o1 = 0.f;
  #pragma unroll
  for (int k = 0; k < 8; ++k) { o0 += w[k] * g0[k]; o1 += w[k] * g1[k]; }
  o0 = fmaxf(fmaf(o0, inv, bias[c0]), 0.f);
  o1 = fmaxf(fmaf(o1, inv, bias[c1]), 0.f);
  if (!FINAL) {
    float2 o; o.x = o0; o.y = o1;
    *(float2*)(xout + (size_t)n * HIDC + c0) = o;
  } else {
    #pragma unroll
    for (int cls = 0; cls < 3; ++cls) {
      float p = wave_sum(o0 * Wf[c0 * 3 + cls] + o1 * Wf[c1 * 3 + cls]);
      if (lane == 0) out[n * 3 + cls] = p + bf[cls];
    }
  }
}

extern "C" void kernel_launch(void* const* d_in, const int* in_sizes, int n_in,
                              void* d_out, int out_size, void* d_ws, size_t ws_size,
                              hipStream_t stream) {
  const float* coord = (const float*)d_in[0];
  const float* feat  = (const float*)d_in[1];
  const int*   batch = (const int*)d_in[2];
  const float* Wl0 = (const float*)d_in[3];
  const float* bl0 = (const float*)d_in[4];
  const float* Wr0 = (const float*)d_in[5];
  const float* br0 = (const float*)d_in[6];
  const float* att0  = (const float*)d_in[7];
  const float* bias0 = (const float*)d_in[8];
  const float* Wl1 = (const float*)d_in[9];
  const float* bl1 = (const float*)d_in[10];
  const float* Wr1 = (const float*)d_in[11];
  const float* br1 = (const float*)d_in[12];
  const float* att1  = (const float*)d_in[13];
  const float* bias1 = (const float*)d_in[14];
  const float* Wl2 = (const float*)d_in[15];
  const float* bl2 = (const float*)d_in[16];
  const float* Wr2 = (const float*)d_in[17];
  const float* br2 = (const float*)d_in[18];
  const float* att2  = (const float*)d_in[19];
  const float* bias2 = (const float*)d_in[20];
  const float* Wf = (const float*)d_in[21];
  const float* bf = (const float*)d_in[22];
  float* out = (float*)d_out;

  char* ws = (char*)d_ws;
  int*   knn = (int*)ws;                                   // 512 KB
  float* xl  = (float*)(ws + (512 << 10));                 // 8 MB
  float* xr  = xl + (size_t)NNODES * HIDC;                 // 8 MB
  float* xb0 = xr + (size_t)NNODES * HIDC;                 // 8 MB
  float* xb1 = xb0 + (size_t)NNODES * HIDC;                // 8 MB

  knn_kernel<<<NNODES / 8, 512, 0, stream>>>(coord, batch, knn);

  lin2_kernel<6><<<NNODES / 32, 256, 0, stream>>>(feat, Wl0, bl0, Wr0, br0, xl, xr);
  gat_attn_kernel<false><<<NNODES / 4, 256, 0, stream>>>(xl, xr, knn, att0, bias0, xb0,
                                                         nullptr, nullptr, nullptr);

  lin2_kernel<128><<<NNODES / 32, 256, 0, stream>>>(xb0, Wl1, bl1, Wr1, br1, xl, xr);
  gat_attn_kernel<false><<<NNODES / 4, 256, 0, stream>>>(xl, xr, knn, att1, bias1, xb1,
                                                         nullptr, nullptr, nullptr);

  lin2_kernel<128><<<NNODES / 32, 256, 0, stream>>>(xb1, Wl2, bl2, Wr2, br2, xl, xr);
  gat_attn_kernel<true><<<NNODES / 4, 256, 0, stream>>>(xl, xr, knn, att2, bias2, nullptr,
                                                        Wf, bf, out);
}